// Round 4
// baseline (231.753 us; speedup 1.0000x reference)
//
#include <hip/hip_runtime.h>

// Classical Gram-Schmidt, 16 vectors x dim-256, 32768 independent rows, fp32.
// Layout (16, 32768, 256).
//
// R3 change: TWO rows per wave64. Lane l owns elements [4l,4l+4) of each of
// the 16 vectors of BOTH rows (2 x 16 x float4 = 128 VGPRs of state). Every
// dependent chain (dot-reduce -> axpy -> norm -> rsqrt) has an independent
// twin from the other row -> the scheduler always has issue-ready work to
// cover DPP/readlane/rsqrt latency. Rows are adjacent (2b, 2b+1) so paired
// loads/stores form 2 KB contiguous bursts.

constexpr int NM  = 16;      // vectors per row
constexpr int NR  = 32768;   // rows
constexpr int D4  = 64;      // 256/4 floats per lane
constexpr int RPW = 2;       // rows per wave

// One DPP-add step: x + permuted(x); masked-out rows receive old=0.
template <int CTRL, int RMASK>
__device__ __forceinline__ float dpp_add(float x) {
    int xi = __builtin_bit_cast(int, x);
    int yi = __builtin_amdgcn_update_dpp(0, xi, CTRL, RMASK, 0xF, false);
    return x + __builtin_bit_cast(float, yi);
}

// Full 64-lane sum; result broadcast through an SGPR (readlane 63).
__device__ __forceinline__ float wave_sum64(float x) {
    x = dpp_add<0xB1,  0xF>(x);   // quad_perm(1,0,3,2) : lane^1
    x = dpp_add<0x4E,  0xF>(x);   // quad_perm(2,3,0,1) : lane^2
    x = dpp_add<0x141, 0xF>(x);   // row_half_mirror    : within 8
    x = dpp_add<0x140, 0xF>(x);   // row_mirror         : within 16
    x = dpp_add<0x142, 0xA>(x);   // row_bcast15 -> rows 1,3
    x = dpp_add<0x143, 0xC>(x);   // row_bcast31 -> rows 2,3 ; lane63 = total
    int s = __builtin_amdgcn_readlane(__builtin_bit_cast(int, x), 63);
    return __builtin_bit_cast(float, s);
}

__device__ __forceinline__ float dot4(const float4& a, const float4& b) {
    return a.x * b.x + a.y * b.y + a.z * b.z + a.w * b.w;
}

__device__ __forceinline__ void axpy_sub(float4& y, float a, const float4& x) {
    y.x -= a * x.x; y.y -= a * x.y; y.z -= a * x.z; y.w -= a * x.w;
}

__global__ __launch_bounds__(64) void gs_kernel(const float* __restrict__ x,
                                                float* __restrict__ out) {
    const int lane = threadIdx.x;
    const int r0   = blockIdx.x * RPW;   // rows r0, r0+1

    const float4* __restrict__ xi = reinterpret_cast<const float4*>(x);
    float4* __restrict__ oo       = reinterpret_cast<float4*>(out);

    // Load both rows' 16 vectors; paired rows are adjacent in memory.
    float4 v[RPW][NM];
#pragma unroll
    for (int i = 0; i < NM; ++i) {
#pragma unroll
        for (int r = 0; r < RPW; ++r) {
            v[r][i] = xi[(size_t)(i * NR + r0 + r) * D4 + lane];
        }
    }

    // Normalize v[r][i] (safe-div) for both rows and store.
    auto finalize = [&](int i) {
        float s[RPW];
#pragma unroll
        for (int r = 0; r < RPW; ++r) s[r] = wave_sum64(dot4(v[r][i], v[r][i]));
#pragma unroll
        for (int r = 0; r < RPW; ++r) {
            float inv = (s[r] > 0.0f) ? rsqrtf(s[r]) : 0.0f;
            v[r][i].x *= inv; v[r][i].y *= inv; v[r][i].z *= inv; v[r][i].w *= inv;
            oo[(size_t)(i * NR + r0 + r) * D4 + lane] = v[r][i];
        }
    };

    finalize(0);

    // Classical GS (matches reference): all coefs from original v[i],
    // then one subtraction pass, then normalize. r-innermost everywhere
    // so the two rows' chains arrive pre-interleaved at the scheduler.
#pragma unroll
    for (int i = 1; i < NM; ++i) {
        float c[RPW][NM - 1];
#pragma unroll
        for (int k = 0; k < i; ++k) {
#pragma unroll
            for (int r = 0; r < RPW; ++r) {
                c[r][k] = wave_sum64(dot4(v[r][i], v[r][k]));
            }
        }
#pragma unroll
        for (int k = 0; k < i; ++k) {
#pragma unroll
            for (int r = 0; r < RPW; ++r) {
                axpy_sub(v[r][i], c[r][k], v[r][k]);
            }
        }
        finalize(i);
    }
}

extern "C" void kernel_launch(void* const* d_in, const int* in_sizes, int n_in,
                              void* d_out, int out_size, void* d_ws, size_t ws_size,
                              hipStream_t stream) {
    const float* x = (const float*)d_in[0];
    float* out     = (float*)d_out;
    dim3 grid(NR / RPW);   // one wave per block, 2 rows per wave
    dim3 block(64);
    hipLaunchKernelGGL(gs_kernel, grid, block, 0, stream, x, out);
}

// Round 5
// 207.655 us; speedup vs baseline: 1.1160x; 1.1160x over previous
//
#include <hip/hip_runtime.h>

// Classical Gram-Schmidt, 16 vectors x dim-256, 32768 independent rows, fp32.
// Layout (16, 32768, 256). One wave64 per row; lane l owns elements
// [4l, 4l+4) of each vector (16 x float4 = 64 VGPRs of state).
//
// R4 change: remove the per-iteration norm REDUCTION via the CGS identity
//   ||w||^2 = ||v||^2 - sum_k c_k^2.
// The post-axpy norm-dot + DPP chain + readlane (~90-120 serial cycles per
// iteration, x16) vanishes; rsqrt overlaps the axpy accumulation, and the
// normalization scale fuses into the subtraction. Sum-chains split 2-way to
// halve FMA depth. 1 row/wave, 64-thread blocks (R2/R3 showed 2 rows/wave
// and block-level reordering are neutral-to-negative).

constexpr int NM = 16;      // vectors per row
constexpr int NR = 32768;   // rows
constexpr int D4 = 64;      // 256/4 floats per lane

// One DPP-add step: x + permuted(x); masked-out rows receive old=0.
template <int CTRL, int RMASK>
__device__ __forceinline__ float dpp_add(float x) {
    int xi = __builtin_bit_cast(int, x);
    int yi = __builtin_amdgcn_update_dpp(0, xi, CTRL, RMASK, 0xF, false);
    return x + __builtin_bit_cast(float, yi);
}

// Full 64-lane sum; result broadcast through an SGPR (readlane 63).
__device__ __forceinline__ float wave_sum64(float x) {
    x = dpp_add<0xB1,  0xF>(x);   // quad_perm(1,0,3,2) : lane^1
    x = dpp_add<0x4E,  0xF>(x);   // quad_perm(2,3,0,1) : lane^2
    x = dpp_add<0x141, 0xF>(x);   // row_half_mirror    : within 8
    x = dpp_add<0x140, 0xF>(x);   // row_mirror         : within 16
    x = dpp_add<0x142, 0xA>(x);   // row_bcast15 -> rows 1,3
    x = dpp_add<0x143, 0xC>(x);   // row_bcast31 -> rows 2,3 ; lane63 = total
    int s = __builtin_amdgcn_readlane(__builtin_bit_cast(int, x), 63);
    return __builtin_bit_cast(float, s);
}

__device__ __forceinline__ float dot4(const float4& a, const float4& b) {
    return (a.x * b.x + a.y * b.y) + (a.z * b.z + a.w * b.w);
}

__global__ __launch_bounds__(64) void gs_kernel(const float* __restrict__ x,
                                                float* __restrict__ out) {
    const int lane = threadIdx.x;
    const int row  = blockIdx.x;

    const float4* __restrict__ xi = reinterpret_cast<const float4*>(x);
    float4* __restrict__ oo       = reinterpret_cast<float4*>(out);

    float4 v[NM];
#pragma unroll
    for (int i = 0; i < NM; ++i) {
        v[i] = xi[(size_t)(i * NR + row) * D4 + lane];
    }

    // q0 = v0 / ||v0|| (safe).
    {
        float s   = wave_sum64(dot4(v[0], v[0]));
        float inv = (s > 0.0f) ? rsqrtf(s) : 0.0f;
        v[0].x *= inv; v[0].y *= inv; v[0].z *= inv; v[0].w *= inv;
        oo[(size_t)(0 * NR + row) * D4 + lane] = v[0];
    }

#pragma unroll
    for (int i = 1; i < NM; ++i) {
        // i+1 independent reductions: ||v_i||^2 and the i coefficients.
        float nn = wave_sum64(dot4(v[i], v[i]));
        float c[NM - 1];
#pragma unroll
        for (int k = 0; k < i; ++k) {
            c[k] = wave_sum64(dot4(v[i], v[k]));   // SGPR-resident
        }

        // ||w||^2 = ||v||^2 - sum c^2  (2-way split chains).
        float s2a = 0.0f, s2b = 0.0f;
#pragma unroll
        for (int k = 0; k < i; k += 2) s2a = fmaf(c[k], c[k], s2a);
#pragma unroll
        for (int k = 1; k < i; k += 2) s2b = fmaf(c[k], c[k], s2b);
        float s   = nn - (s2a + s2b);
        float inv = (s > 0.0f) ? rsqrtf(s) : 0.0f;   // overlaps acc below

        // acc = sum_k c_k q_k, 2 independent accumulators.
        float4 a0 = make_float4(0.f, 0.f, 0.f, 0.f);
        float4 a1 = make_float4(0.f, 0.f, 0.f, 0.f);
#pragma unroll
        for (int k = 0; k < i; k += 2) {
            a0.x = fmaf(c[k], v[k].x, a0.x);
            a0.y = fmaf(c[k], v[k].y, a0.y);
            a0.z = fmaf(c[k], v[k].z, a0.z);
            a0.w = fmaf(c[k], v[k].w, a0.w);
        }
#pragma unroll
        for (int k = 1; k < i; k += 2) {
            a1.x = fmaf(c[k], v[k].x, a1.x);
            a1.y = fmaf(c[k], v[k].y, a1.y);
            a1.z = fmaf(c[k], v[k].z, a1.z);
            a1.w = fmaf(c[k], v[k].w, a1.w);
        }

        // q_i = (v_i - acc) * inv, fused; store immediately.
        v[i].x = (v[i].x - (a0.x + a1.x)) * inv;
        v[i].y = (v[i].y - (a0.y + a1.y)) * inv;
        v[i].z = (v[i].z - (a0.z + a1.z)) * inv;
        v[i].w = (v[i].w - (a0.w + a1.w)) * inv;
        oo[(size_t)(i * NR + row) * D4 + lane] = v[i];
    }
}

extern "C" void kernel_launch(void* const* d_in, const int* in_sizes, int n_in,
                              void* d_out, int out_size, void* d_ws, size_t ws_size,
                              hipStream_t stream) {
    const float* x = (const float*)d_in[0];
    float* out     = (float*)d_out;
    dim3 grid(NR);      // one wave (64 threads) per row
    dim3 block(64);
    hipLaunchKernelGGL(gs_kernel, grid, block, 0, stream, x, out);
}

// Round 6
// 198.649 us; speedup vs baseline: 1.1666x; 1.0453x over previous
//
#include <hip/hip_runtime.h>
#include <hip/hip_bf16.h>

// Cholesky-QR formulation of classical Gram-Schmidt.
// 16 vectors x dim-256 per row, 32768 rows, fp32, layout (16, 32768, 256).
//
// Identity: with G = V V^T (16x16 Gram) and G = L L^T (Cholesky), the CGS
// coefficients are exactly L[i][k] (= <v_i, q_k>) and the norms are L[i][i].
// So Q = L^{-1} V reproduces CGS output with ZERO per-element reductions:
//   - G via MFMA (bf16 hi/lo split, 3 terms: hi.hi + hi.lo + lo.hi)
//   - fused right-looking Cholesky + forward substitution: per column j,
//     readlane-broadcast L[t][j] serves BOTH the Cholesky trailing update
//     and the q_j subtraction from future v_t. Pure FMA, no DPP chains.
// Layout-immunity: A-frag and B-frag are the SAME registers (symmetric
// product) so the result is independent of the HW k-position map; G is
// symmetric so C/D row/col orientation doesn't matter either.

constexpr int NM   = 16;     // vectors per row
constexpr int NR   = 32768;  // rows
constexpr int D    = 256;    // vector dim
constexpr int D4   = 64;     // floats4 per vector
constexpr int LROW = 264;    // padded bf16 row stride in LDS (breaks 128-word stride)
constexpr int GROW = 20;     // padded G row stride (floats, 80B -> 16B aligned)

typedef __attribute__((ext_vector_type(8))) short short8v;  // 8 x bf16
typedef __attribute__((ext_vector_type(4))) float f32x4;

__device__ __forceinline__ float rl(float x, int lane) {
    return __builtin_bit_cast(float,
        __builtin_amdgcn_readlane(__builtin_bit_cast(int, x), lane));
}

__device__ __forceinline__ unsigned short bfbits(__hip_bfloat16 h) {
    return __builtin_bit_cast(unsigned short, h);
}

__global__ __launch_bounds__(64) void gs_kernel(const float* __restrict__ x,
                                                float* __restrict__ out) {
    __shared__ __align__(16) unsigned short sm_hi[NM * LROW];  // 8448 B
    __shared__ __align__(16) unsigned short sm_lo[NM * LROW];  // 8448 B
    __shared__ __align__(16) float          sm_G[NM * GROW];   // 1280 B

    const int lane = threadIdx.x;
    const int row  = blockIdx.x;
    const int vec  = lane & 15;   // MFMA row/col owned by this lane
    const int kgrp = lane >> 4;   // k-group 0..3

    const float4* __restrict__ xi = reinterpret_cast<const float4*>(x);
    float4* __restrict__ oo       = reinterpret_cast<float4*>(out);

    // Load the 16 vectors (lane l owns elems 4l..4l+3, coalesced 1 KB/inst).
    float4 v[NM];
#pragma unroll
    for (int i = 0; i < NM; ++i)
        v[i] = xi[(size_t)(i * NR + row) * D4 + lane];

    // Stage bf16 hi/lo split to LDS (consumed progressively as loads land).
#pragma unroll
    for (int i = 0; i < NM; ++i) {
        float4 f = v[i];
        __hip_bfloat16 h0 = __float2bfloat16(f.x);
        __hip_bfloat16 h1 = __float2bfloat16(f.y);
        __hip_bfloat16 h2 = __float2bfloat16(f.z);
        __hip_bfloat16 h3 = __float2bfloat16(f.w);
        __hip_bfloat16 l0 = __float2bfloat16(f.x - __bfloat162float(h0));
        __hip_bfloat16 l1 = __float2bfloat16(f.y - __bfloat162float(h1));
        __hip_bfloat16 l2 = __float2bfloat16(f.z - __bfloat162float(h2));
        __hip_bfloat16 l3 = __float2bfloat16(f.w - __bfloat162float(h3));
        ushort4 hp = make_ushort4(bfbits(h0), bfbits(h1), bfbits(h2), bfbits(h3));
        ushort4 lp = make_ushort4(bfbits(l0), bfbits(l1), bfbits(l2), bfbits(l3));
        *reinterpret_cast<ushort4*>(&sm_hi[i * LROW + 4 * lane]) = hp;
        *reinterpret_cast<ushort4*>(&sm_lo[i * LROW + 4 * lane]) = lp;
    }
    __syncthreads();

    // G = V V^T via MFMA. Frag for lane l: vector (l&15), k-slice
    // c*32 + (l>>4)*8 .. +8. Same registers fed as A and B (symmetric).
    f32x4 g = {0.0f, 0.0f, 0.0f, 0.0f};
#pragma unroll
    for (int c = 0; c < 8; ++c) {
        const int off = vec * LROW + c * 32 + kgrp * 8;
        short8v ah = *reinterpret_cast<const short8v*>(&sm_hi[off]);
        short8v al = *reinterpret_cast<const short8v*>(&sm_lo[off]);
        g = __builtin_amdgcn_mfma_f32_16x16x32_bf16(ah, ah, g, 0, 0, 0);
        g = __builtin_amdgcn_mfma_f32_16x16x32_bf16(ah, al, g, 0, 0, 0);
        g = __builtin_amdgcn_mfma_f32_16x16x32_bf16(al, ah, g, 0, 0, 0);
    }

    // Scatter G to LDS (C/D layout: col = lane&15, row = (lane>>4)*4 + r),
    // then each lane gathers its Cholesky row (4-way broadcast, 2-way banks).
#pragma unroll
    for (int r = 0; r < 4; ++r)
        sm_G[(kgrp * 4 + r) * GROW + vec] = g[r];
    __syncthreads();

    float a[NM];
#pragma unroll
    for (int t = 0; t < 4; ++t) {
        f32x4 rr = *reinterpret_cast<const f32x4*>(&sm_G[vec * GROW + t * 4]);
        a[4 * t + 0] = rr[0];
        a[4 * t + 1] = rr[1];
        a[4 * t + 2] = rr[2];
        a[4 * t + 3] = rr[3];
    }

    // Fused right-looking Cholesky + forward substitution. All scalar
    // broadcasts are readlanes of finalized columns; q path is pure fp32 FMA
    // on the original element layout.
#pragma unroll
    for (int j = 0; j < NM; ++j) {
        float p   = rl(a[j], j);                    // pivot = ||w_j||^2
        float inv = (p > 0.0f) ? rsqrtf(p) : 0.0f;  // safe-div
        v[j].x *= inv; v[j].y *= inv; v[j].z *= inv; v[j].w *= inv;   // q_j
        oo[(size_t)(j * NR + row) * D4 + lane] = v[j];
        a[j] *= inv;                                // column j -> L[r][j]
#pragma unroll
        for (int t = j + 1; t < NM; ++t) {
            float u = rl(a[j], t);                  // L[t][j] = <v_t, q_j>
            a[t]  = fmaf(-u, a[j], a[t]);           // Cholesky trailing update
            v[t].x = fmaf(-u, v[j].x, v[t].x);      // v_t -= L[t][j] * q_j
            v[t].y = fmaf(-u, v[j].y, v[t].y);
            v[t].z = fmaf(-u, v[j].z, v[t].z);
            v[t].w = fmaf(-u, v[j].w, v[t].w);
        }
    }
}

extern "C" void kernel_launch(void* const* d_in, const int* in_sizes, int n_in,
                              void* d_out, int out_size, void* d_ws, size_t ws_size,
                              hipStream_t stream) {
    const float* x = (const float*)d_in[0];
    float* out     = (float*)d_out;
    dim3 grid(NR);     // one wave per row
    dim3 block(64);
    hipLaunchKernelGGL(gs_kernel, grid, block, 0, stream, x, out);
}